// Round 1
// baseline (75.687 us; speedup 1.0000x reference)
//
#include <hip/hip_runtime.h>

#define B_TOTAL 32768
#define HDIM    128
#define KDIM    256
#define BROWS   64

typedef __attribute__((ext_vector_type(8))) short bf16x8;
typedef __attribute__((ext_vector_type(4))) float f32x4;

// round-to-nearest-even fp32 -> bf16 (weights, one-time)
__device__ __forceinline__ unsigned rne1(float f) {
    unsigned u = __builtin_bit_cast(unsigned, f);
    return (u + 0x7FFFu + ((u >> 16) & 1u)) >> 16;
}

// cheap round-to-nearest (away on ties) pack of 2 fp32 -> packed bf16x2 (A path, hot loop)
__device__ __forceinline__ unsigned pack2bf(float flo, float fhi) {
    unsigned lo = (__builtin_bit_cast(unsigned, flo) + 0x8000u) >> 16;
    unsigned hi = (__builtin_bit_cast(unsigned, fhi) + 0x8000u) & 0xFFFF0000u;
    return hi | lo;
}

__device__ __forceinline__ float sigmoidf_(float v) {
    return 1.0f / (1.0f + __expf(-v));
}
__device__ __forceinline__ float tanhf_(float v) {
    return 1.0f - 2.0f / (1.0f + __expf(2.0f * v));
}

// Convert W1,W2,Wf,W3 (each [128][256] fp32) into ws as bf16 [4][128][256]
__global__ void wconv_kernel(const float* __restrict__ w1, const float* __restrict__ w2,
                             const float* __restrict__ wf, const float* __restrict__ w3,
                             unsigned int* __restrict__ out) {
    int t = blockIdx.x * 256 + threadIdx.x;   // 32768 threads, 4 elems each
    int i = t * 4;                            // element index 0..131068
    int g = i >> 15;
    int off = i & 32767;
    const float* s = (g == 0) ? w1 : (g == 1) ? w2 : (g == 2) ? wf : w3;
    f32x4 v = *(const f32x4*)(s + off);
    unsigned r0 = rne1(v[0]) | (rne1(v[1]) << 16);
    unsigned r1 = rne1(v[2]) | (rne1(v[3]) << 16);
    out[t * 2 + 0] = r0;
    out[t * 2 + 1] = r1;
}

// One block = 64 batch rows. Wave w computes gate w: [64 x 128] = total[64 x 256] @ Wg^T.
__global__ __launch_bounds__(256, 2) void lstm_kernel(
    const float* __restrict__ x, const float* __restrict__ h, const float* __restrict__ c,
    const unsigned short* __restrict__ wbf,   // [4][128][256] bf16
    const float* __restrict__ b1, const float* __restrict__ b2,
    const float* __restrict__ bfv, const float* __restrict__ b3,
    float* __restrict__ out)
{
    __shared__ float lds[4][64][36];          // 36 KB, +4 pad: row-groups land 2/bank (free)

    const int tid  = threadIdx.x;
    const int wave = tid >> 6;                // gate id 0..3
    const int lane = tid & 63;
    const int col  = lane & 15;               // n (B/D) or m (A) within tile
    const int kgrp = lane >> 4;               // 0..3
    const long b0  = (long)blockIdx.x * BROWS;

    const unsigned short* wg = wbf + (size_t)wave * (HDIM * KDIM);

    f32x4 acc[4][8];
#pragma unroll
    for (int mt = 0; mt < 4; ++mt)
#pragma unroll
        for (int nt = 0; nt < 8; ++nt)
            acc[mt][nt] = (f32x4){0.f, 0.f, 0.f, 0.f};

#pragma unroll
    for (int ks = 0; ks < 8; ++ks) {
        const int kk = ks * 32 + kgrp * 8;    // this lane's k-base (8 contiguous)
        const float* srcbase = (kk < 128) ? (x + kk) : (h + (kk - 128));
        bf16x8 afrag[4];
#pragma unroll
        for (int mt = 0; mt < 4; ++mt) {
            const float* p = srcbase + (b0 + mt * 16 + col) * 128;
            f32x4 lo = *(const f32x4*)(p);
            f32x4 hi = *(const f32x4*)(p + 4);
            union { unsigned u[4]; bf16x8 v; } pk;
            pk.u[0] = pack2bf(lo[0], lo[1]);
            pk.u[1] = pack2bf(lo[2], lo[3]);
            pk.u[2] = pack2bf(hi[0], hi[1]);
            pk.u[3] = pack2bf(hi[2], hi[3]);
            afrag[mt] = pk.v;
        }
#pragma unroll
        for (int nt = 0; nt < 8; ++nt) {
            bf16x8 bfrag = *(const bf16x8*)(wg + (nt * 16 + col) * KDIM + kk);
#pragma unroll
            for (int mt = 0; mt < 4; ++mt)
                acc[mt][nt] = __builtin_amdgcn_mfma_f32_16x16x32_bf16(
                    afrag[mt], bfrag, acc[mt][nt], 0, 0, 0);
        }
    }

    // bias + activation in-register (wave 2 = candidate tanh; others sigmoid)
    const float* bptr = (wave == 0) ? b1 : (wave == 1) ? b2 : (wave == 2) ? bfv : b3;
    float bias[8];
#pragma unroll
    for (int nt = 0; nt < 8; ++nt) bias[nt] = bptr[nt * 16 + col];

#pragma unroll
    for (int mt = 0; mt < 4; ++mt)
#pragma unroll
        for (int nt = 0; nt < 8; ++nt)
#pragma unroll
            for (int j = 0; j < 4; ++j) {
                float v = acc[mt][nt][j] + bias[nt];
                acc[mt][nt][j] = (wave == 2) ? tanhf_(v) : sigmoidf_(v);
            }

    float* out_h = out;
    float* out_c = out + (size_t)B_TOTAL * HDIM;

    // 4 chunks of 32 gate-columns: exchange via LDS, combine, store
#pragma unroll 1
    for (int ci = 0; ci < 4; ++ci) {
#pragma unroll
        for (int half = 0; half < 2; ++half) {
            int nt = ci * 2 + half;
#pragma unroll
            for (int mt = 0; mt < 4; ++mt)
#pragma unroll
                for (int j = 0; j < 4; ++j)
                    lds[wave][mt * 16 + kgrp * 4 + j][half * 16 + col] = acc[mt][nt][j];
        }
        __syncthreads();
        {
            const int row  = tid >> 2;            // 0..63
            const int colb = (tid & 3) * 8;       // 0,8,16,24
            const long grow = b0 + row;
            const int  gcol = ci * 32 + colb;
            const float* crow = c + grow * 128 + gcol;
            f32x4 cv0 = *(const f32x4*)(crow);
            f32x4 cv1 = *(const f32x4*)(crow + 4);
            f32x4 nh0, nh1, nc0, nc1;
#pragma unroll
            for (int j = 0; j < 8; ++j) {
                float g1 = lds[0][row][colb + j];
                float g2 = lds[1][row][colb + j];
                float gf = lds[2][row][colb + j];
                float g3 = lds[3][row][colb + j];
                float cin = (j < 4) ? cv0[j] : cv1[j - 4];
                float nc = cin * g1 + g2 * gf;
                float nh = tanhf_(nc) * g3;
                if (j < 4) { nc0[j] = nc; nh0[j] = nh; }
                else       { nc1[j - 4] = nc; nh1[j - 4] = nh; }
            }
            float* ohp = out_h + grow * 128 + gcol;
            float* ocp = out_c + grow * 128 + gcol;
            *(f32x4*)(ohp)     = nh0;
            *(f32x4*)(ohp + 4) = nh1;
            *(f32x4*)(ocp)     = nc0;
            *(f32x4*)(ocp + 4) = nc1;
        }
        __syncthreads();
    }
}

extern "C" void kernel_launch(void* const* d_in, const int* in_sizes, int n_in,
                              void* d_out, int out_size, void* d_ws, size_t ws_size,
                              hipStream_t stream) {
    (void)in_sizes; (void)n_in; (void)out_size; (void)ws_size;
    const float* x  = (const float*)d_in[0];
    const float* h  = (const float*)d_in[1];
    const float* c  = (const float*)d_in[2];
    const float* W1 = (const float*)d_in[3];
    const float* b1 = (const float*)d_in[4];
    const float* W2 = (const float*)d_in[5];
    const float* b2 = (const float*)d_in[6];
    const float* Wf = (const float*)d_in[7];
    const float* bf = (const float*)d_in[8];
    const float* W3 = (const float*)d_in[9];
    const float* b3 = (const float*)d_in[10];

    unsigned short* wbf = (unsigned short*)d_ws;   // 256 KB bf16 weights

    wconv_kernel<<<128, 256, 0, stream>>>(W1, W2, Wf, W3, (unsigned int*)wbf);
    lstm_kernel<<<B_TOTAL / BROWS, 256, 0, stream>>>(
        x, h, c, wbf, b1, b2, bf, b3, (float*)d_out);
}

// Round 2
// 62.959 us; speedup vs baseline: 1.2022x; 1.2022x over previous
//
#include <hip/hip_runtime.h>

#define B_TOTAL 32768
#define HDIM    128
#define KDIM    256
#define BROWS   32

typedef __attribute__((ext_vector_type(8))) short bf16x8;
typedef __attribute__((ext_vector_type(4))) float f32x4;
typedef __attribute__((ext_vector_type(2))) unsigned u32x2;
typedef __attribute__((ext_vector_type(4))) unsigned u32x4;

// round-to-nearest-even fp32 -> bf16
__device__ __forceinline__ unsigned rne1(float f) {
    unsigned u = __builtin_bit_cast(unsigned, f);
    return (u + 0x7FFFu + ((u >> 16) & 1u)) >> 16;
}

// fast pack of 2 fp32 -> bf16x2 (round-to-nearest, ties-away)
__device__ __forceinline__ unsigned pack2bf(float flo, float fhi) {
    unsigned lo = (__builtin_bit_cast(unsigned, flo) + 0x8000u) >> 16;
    unsigned hi = (__builtin_bit_cast(unsigned, fhi) + 0x8000u) & 0xFFFF0000u;
    return hi | lo;
}

__device__ __forceinline__ float sigmoidf_(float v) {
    return 1.0f / (1.0f + __expf(-v));
}
__device__ __forceinline__ float tanhf_(float v) {
    return 1.0f - 2.0f / (1.0f + __expf(2.0f * v));
}

// Convert W1,W2,Wf,W3 ([128][256] fp32 each) into fragment-linear bf16:
// chunk c = g*64 + ks*8 + nt  (1 KB each); within chunk lane l holds 16 B:
//   W_g[nt*16 + (l&15)][ks*32 + (l>>4)*8 + e], e=0..7
__global__ void wconv_kernel(const float* __restrict__ w1, const float* __restrict__ w2,
                             const float* __restrict__ wf, const float* __restrict__ w3,
                             u32x4* __restrict__ out) {
    int T = blockIdx.x * 256 + threadIdx.x;   // 16384 threads
    int g  = T >> 12;
    int ks = (T >> 9) & 7;
    int nt = (T >> 6) & 7;
    int l  = T & 63;
    int colw = l & 15, kg = l >> 4;
    const float* W = (g == 0) ? w1 : (g == 1) ? w2 : (g == 2) ? wf : w3;
    const float* s = W + (nt * 16 + colw) * 256 + ks * 32 + kg * 8;
    f32x4 lo = *(const f32x4*)s;
    f32x4 hi = *(const f32x4*)(s + 4);
    u32x4 r;
    r[0] = rne1(lo[0]) | (rne1(lo[1]) << 16);
    r[1] = rne1(lo[2]) | (rne1(lo[3]) << 16);
    r[2] = rne1(hi[0]) | (rne1(hi[1]) << 16);
    r[3] = rne1(hi[2]) | (rne1(hi[3]) << 16);
    out[T] = r;
}

// Block = 32 batch rows, 4 waves; wave w computes gate w over [32 x 128].
__global__ __launch_bounds__(256, 4) void lstm_kernel(
    const float* __restrict__ x, const float* __restrict__ h, const float* __restrict__ c,
    const bf16x8* __restrict__ wfrag,         // fragment-linear bf16 weights
    const float* __restrict__ b1, const float* __restrict__ b2,
    const float* __restrict__ bfv, const float* __restrict__ b3,
    float* __restrict__ out)
{
    // union: A-tile (32 rows x 256 k bf16, swizzled) = 16 KB; epilogue
    // exchange float[4][32][34] = 17408 B.  Stride 34 => ~2-way LDS (free).
    __shared__ __align__(16) char smem[4 * 32 * 34 * 4];

    const int tid  = threadIdx.x;
    const int wave = tid >> 6;                // gate id 0..3
    const int lane = tid & 63;
    const int col16 = lane & 15;
    const int kgrp  = lane >> 4;
    const long b0  = (long)blockIdx.x * BROWS;

    // ---- stage A (x|h rows b0..b0+31) into LDS as swizzled bf16 ----
    {
        const int half = tid >> 7;            // 0: x-half (k 0..127), 1: h-half
        const int tt   = tid & 127;
        const float* src = (half ? h : x) + b0 * 128;
#pragma unroll
        for (int j = 0; j < 8; ++j) {
            const int F = j * 512 + tt * 4;   // float idx within 16KB half (coalesced)
            f32x4 v = *(const f32x4*)(src + F);
            const int r = F >> 7;             // local row 0..31
            const int k = (F & 127) + half * 128;
            unsigned byte = (unsigned)(r * 512 + k * 2) ^ ((unsigned)(r & 7) << 4);
            u32x2 p;
            p[0] = pack2bf(v[0], v[1]);
            p[1] = pack2bf(v[2], v[3]);
            *(u32x2*)(smem + byte) = p;
        }
    }
    __syncthreads();

    // ---- MFMA: [32 x 128] = A[32 x 256] @ Wg^T ----
    f32x4 acc[2][8];
#pragma unroll
    for (int mt = 0; mt < 2; ++mt)
#pragma unroll
        for (int nt = 0; nt < 8; ++nt)
            acc[mt][nt] = (f32x4){0.f, 0.f, 0.f, 0.f};

    const bf16x8* wg = wfrag + (size_t)(wave * 64) * 64 + lane;

#pragma unroll
    for (int ks = 0; ks < 8; ++ks) {
        bf16x8 af[2];
#pragma unroll
        for (int mt = 0; mt < 2; ++mt) {
            const int row = mt * 16 + col16;
            unsigned byte = (unsigned)(row * 512 + ks * 64 + kgrp * 16)
                          ^ ((unsigned)(row & 7) << 4);
            af[mt] = *(const bf16x8*)(smem + byte);
        }
#pragma unroll
        for (int nt = 0; nt < 8; ++nt) {
            bf16x8 bfrag = wg[(ks * 8 + nt) * 64];
            acc[0][nt] = __builtin_amdgcn_mfma_f32_16x16x32_bf16(af[0], bfrag, acc[0][nt], 0, 0, 0);
            acc[1][nt] = __builtin_amdgcn_mfma_f32_16x16x32_bf16(af[1], bfrag, acc[1][nt], 0, 0, 0);
        }
    }

    // ---- bias + activation in-register (wave 2 = tanh candidate) ----
    const float* bptr = (wave == 0) ? b1 : (wave == 1) ? b2 : (wave == 2) ? bfv : b3;
    float bias[8];
#pragma unroll
    for (int nt = 0; nt < 8; ++nt) bias[nt] = bptr[nt * 16 + col16];

#pragma unroll
    for (int mt = 0; mt < 2; ++mt)
#pragma unroll
        for (int nt = 0; nt < 8; ++nt)
#pragma unroll
            for (int j = 0; j < 4; ++j) {
                float v = acc[mt][nt][j] + bias[nt];
                acc[mt][nt][j] = (wave == 2) ? tanhf_(v) : sigmoidf_(v);
            }

    float* out_h = out;
    float* out_c = out + (size_t)B_TOTAL * HDIM;
    float* ex = (float*)smem;                 // [4][32][34]
    __syncthreads();                          // A-tile dead; safe to reuse

    // ---- 4 chunks of 32 gate-cols: LDS exchange, combine with c, store ----
#pragma unroll 1
    for (int ci = 0; ci < 4; ++ci) {
#pragma unroll
        for (int hf = 0; hf < 2; ++hf) {
            const int nt = ci * 2 + hf;
#pragma unroll
            for (int mt = 0; mt < 2; ++mt)
#pragma unroll
                for (int j = 0; j < 4; ++j)
                    ex[(wave * 32 + mt * 16 + kgrp * 4 + j) * 34 + hf * 16 + col16]
                        = acc[mt][nt][j];
        }
        __syncthreads();
        {
            const int row = tid >> 3;         // 0..31
            const int cb  = (tid & 7) * 4;    // 0..28
            const long grow = b0 + row;
            const int  gcol = ci * 32 + cb;
            f32x4 cv = *(const f32x4*)(c + grow * 128 + gcol);
            f32x4 nh, nc;
#pragma unroll
            for (int j = 0; j < 4; ++j) {
                float g1 = ex[(0 * 32 + row) * 34 + cb + j];
                float g2 = ex[(1 * 32 + row) * 34 + cb + j];
                float gf = ex[(2 * 32 + row) * 34 + cb + j];
                float g3 = ex[(3 * 32 + row) * 34 + cb + j];
                float ncv = cv[j] * g1 + g2 * gf;
                nc[j] = ncv;
                nh[j] = tanhf_(ncv) * g3;
            }
            *(f32x4*)(out_h + grow * 128 + gcol) = nh;
            *(f32x4*)(out_c + grow * 128 + gcol) = nc;
        }
        __syncthreads();
    }
}

extern "C" void kernel_launch(void* const* d_in, const int* in_sizes, int n_in,
                              void* d_out, int out_size, void* d_ws, size_t ws_size,
                              hipStream_t stream) {
    (void)in_sizes; (void)n_in; (void)out_size; (void)ws_size;
    const float* x  = (const float*)d_in[0];
    const float* h  = (const float*)d_in[1];
    const float* c  = (const float*)d_in[2];
    const float* W1 = (const float*)d_in[3];
    const float* b1 = (const float*)d_in[4];
    const float* W2 = (const float*)d_in[5];
    const float* b2 = (const float*)d_in[6];
    const float* Wf = (const float*)d_in[7];
    const float* bf = (const float*)d_in[8];
    const float* W3 = (const float*)d_in[9];
    const float* b3 = (const float*)d_in[10];

    wconv_kernel<<<64, 256, 0, stream>>>(W1, W2, Wf, W3, (u32x4*)d_ws);
    lstm_kernel<<<B_TOTAL / BROWS, 256, 0, stream>>>(
        x, h, c, (const bf16x8*)d_ws, b1, b2, bf, b3, (float*)d_out);
}

// Round 3
// 52.169 us; speedup vs baseline: 1.4508x; 1.2068x over previous
//
#include <hip/hip_runtime.h>

#define B_TOTAL 32768
#define HDIM    128
#define KDIM    256
#define BROWS   32

typedef __attribute__((ext_vector_type(8)))  short    bf16x8;
typedef __attribute__((ext_vector_type(4)))  float    f32x4;
typedef __attribute__((ext_vector_type(16))) float    f32x16;
typedef __attribute__((ext_vector_type(2)))  unsigned u32x2;
typedef __attribute__((ext_vector_type(4)))  unsigned u32x4;

// round-to-nearest-even fp32 -> bf16
__device__ __forceinline__ unsigned rne1(float f) {
    unsigned u = __builtin_bit_cast(unsigned, f);
    return (u + 0x7FFFu + ((u >> 16) & 1u)) >> 16;
}

// fast pack of 2 fp32 -> bf16x2
__device__ __forceinline__ unsigned pack2bf(float flo, float fhi) {
    unsigned lo = (__builtin_bit_cast(unsigned, flo) + 0x8000u) >> 16;
    unsigned hi = (__builtin_bit_cast(unsigned, fhi) + 0x8000u) & 0xFFFF0000u;
    return hi | lo;
}

__device__ __forceinline__ float sigmoidf_(float v) {
    return 1.0f / (1.0f + __expf(-v));
}
__device__ __forceinline__ float tanhf_(float v) {
    return 1.0f - 2.0f / (1.0f + __expf(2.0f * v));
}

// Weights -> fragment-linear bf16 for mfma_f32_32x32x16 B-operand.
// Frag F = (g*4 + w)*16 + ks (1 KB each); lane l holds 16 B:
//   W_g[n = w*32 + (l&31)][k = ks*16 + (l>>5)*8 + e], e=0..7
__global__ void wconv_kernel(const float* __restrict__ w1, const float* __restrict__ w2,
                             const float* __restrict__ wf, const float* __restrict__ w3,
                             u32x4* __restrict__ out) {
    int T = blockIdx.x * 256 + threadIdx.x;   // 16384 threads
    int g  = T >> 12;
    int w  = (T >> 10) & 3;
    int ks = (T >> 6) & 15;
    int l  = T & 63;
    const float* W = (g == 0) ? w1 : (g == 1) ? w2 : (g == 2) ? wf : w3;
    const float* s = W + (w * 32 + (l & 31)) * 256 + ks * 16 + (l >> 5) * 8;
    f32x4 lo = *(const f32x4*)s;
    f32x4 hi = *(const f32x4*)(s + 4);
    u32x4 r;
    r[0] = rne1(lo[0]) | (rne1(lo[1]) << 16);
    r[1] = rne1(lo[2]) | (rne1(lo[3]) << 16);
    r[2] = rne1(hi[0]) | (rne1(hi[1]) << 16);
    r[3] = rne1(hi[2]) | (rne1(hi[3]) << 16);
    out[T] = r;
}

// Block = 32 rows, 4 waves. Wave w computes ALL 4 gates for cols [32w,32w+32)
// over all 32 rows via mfma_32x32x16 -> combine is fully in-register.
__global__ __launch_bounds__(256, 4) void lstm_kernel(
    const float* __restrict__ x, const float* __restrict__ h, const float* __restrict__ c,
    const bf16x8* __restrict__ wfrag,
    const float* __restrict__ b1, const float* __restrict__ b2,
    const float* __restrict__ bfv, const float* __restrict__ b3,
    float* __restrict__ out)
{
    __shared__ __align__(16) char smem[32 * 512];   // A-tile: 32 rows x 256 k bf16, swizzled

    const int tid  = threadIdx.x;
    const int wave = tid >> 6;                // col-slice 0..3
    const int lane = tid & 63;
    const int col  = lane & 31;
    const int hi   = lane >> 5;
    const long b0  = (long)blockIdx.x * BROWS;

    // ---- stage A (x|h rows) into LDS as swizzled bf16 ----
    {
        const int half = tid >> 7;            // 0: x (k 0..127), 1: h (k 128..255)
        const int tt   = tid & 127;
        const float* src = (half ? h : x) + b0 * 128;
#pragma unroll
        for (int j = 0; j < 8; ++j) {
            const int F = j * 512 + tt * 4;
            f32x4 v = *(const f32x4*)(src + F);
            const int r = F >> 7;
            const int k = (F & 127) + half * 128;
            unsigned byte = (unsigned)(r * 512 + k * 2) ^ ((unsigned)(r & 7) << 4);
            u32x2 p;
            p[0] = pack2bf(v[0], v[1]);
            p[1] = pack2bf(v[2], v[3]);
            *(u32x2*)(smem + byte) = p;
        }
    }
    __syncthreads();

    // ---- prefetch c and biases (latency hides under MFMA loop) ----
    const int gcol = wave * 32 + col;
    float cv[16];
#pragma unroll
    for (int r = 0; r < 16; ++r) {
        const int row = (r & 3) + 8 * (r >> 2) + 4 * hi;
        cv[r] = c[(b0 + row) * 128 + gcol];
    }
    const float bias0 = b1[gcol];
    const float bias1 = b2[gcol];
    const float bias2 = bfv[gcol];
    const float bias3 = b3[gcol];

    // ---- MFMA: acc[g] = A[32x256] @ Wg[cols 32w..32w+32)^T ----
    f32x16 acc[4];
#pragma unroll
    for (int g = 0; g < 4; ++g) acc[g] = (f32x16)(0.f);

#pragma unroll 4
    for (int ks = 0; ks < 16; ++ks) {
        const int row = col;                  // lane&31
        unsigned byte = (unsigned)(row * 512 + ks * 32 + hi * 16)
                      ^ ((unsigned)(row & 7) << 4);
        bf16x8 af = *(const bf16x8*)(smem + byte);
#pragma unroll
        for (int g = 0; g < 4; ++g) {
            bf16x8 bfr = wfrag[(size_t)(((g * 4 + wave) * 16) + ks) * 64 + lane];
            acc[g] = __builtin_amdgcn_mfma_f32_32x32x16_bf16(af, bfr, acc[g], 0, 0, 0);
        }
    }

    // ---- epilogue: bias+activation+combine fully in-register ----
    float* out_h = out;
    float* out_c = out + (size_t)B_TOTAL * HDIM;
#pragma unroll
    for (int r = 0; r < 16; ++r) {
        const int row = (r & 3) + 8 * (r >> 2) + 4 * hi;
        const float g1 = sigmoidf_(acc[0][r] + bias0);
        const float g2 = sigmoidf_(acc[1][r] + bias1);
        const float gf = tanhf_(acc[2][r] + bias2);
        const float g3 = sigmoidf_(acc[3][r] + bias3);
        const float nc = cv[r] * g1 + g2 * gf;
        const float nh = tanhf_(nc) * g3;
        const long o = (b0 + row) * 128 + gcol;
        out_h[o] = nh;
        out_c[o] = nc;
    }
}

extern "C" void kernel_launch(void* const* d_in, const int* in_sizes, int n_in,
                              void* d_out, int out_size, void* d_ws, size_t ws_size,
                              hipStream_t stream) {
    (void)in_sizes; (void)n_in; (void)out_size; (void)ws_size;
    const float* x  = (const float*)d_in[0];
    const float* h  = (const float*)d_in[1];
    const float* c  = (const float*)d_in[2];
    const float* W1 = (const float*)d_in[3];
    const float* b1 = (const float*)d_in[4];
    const float* W2 = (const float*)d_in[5];
    const float* b2 = (const float*)d_in[6];
    const float* Wf = (const float*)d_in[7];
    const float* bf = (const float*)d_in[8];
    const float* W3 = (const float*)d_in[9];
    const float* b3 = (const float*)d_in[10];

    wconv_kernel<<<64, 256, 0, stream>>>(W1, W2, Wf, W3, (u32x4*)d_ws);
    lstm_kernel<<<B_TOTAL / BROWS, 256, 0, stream>>>(
        x, h, c, (const bf16x8*)d_ws, b1, b2, bf, b3, (float*)d_out);
}

// Round 4
// 51.497 us; speedup vs baseline: 1.4697x; 1.0130x over previous
//
#include <hip/hip_runtime.h>

#define B_TOTAL 32768
#define HDIM    128
#define KDIM    256
#define BROWS   32

typedef __attribute__((ext_vector_type(8)))  short    bf16x8;
typedef __attribute__((ext_vector_type(4)))  float    f32x4;
typedef __attribute__((ext_vector_type(16))) float    f32x16;
typedef __attribute__((ext_vector_type(4)))  unsigned u32x4;

// round-to-nearest-even fp32 -> bf16 (weights)
__device__ __forceinline__ unsigned rne1(float f) {
    unsigned u = __builtin_bit_cast(unsigned, f);
    return (u + 0x7FFFu + ((u >> 16) & 1u)) >> 16;
}
// fast pack of 2 fp32 -> bf16x2 (A path)
__device__ __forceinline__ unsigned pack2bf(float flo, float fhi) {
    unsigned lo = (__builtin_bit_cast(unsigned, flo) + 0x8000u) >> 16;
    unsigned hi = (__builtin_bit_cast(unsigned, fhi) + 0x8000u) & 0xFFFF0000u;
    return hi | lo;
}

__device__ __forceinline__ float fsig(float v) {       // sigmoid, v_exp+v_rcp
    return __fdividef(1.0f, 1.0f + __expf(-v));
}
__device__ __forceinline__ float ftanh(float v) {      // tanh, v_exp+v_rcp
    return 1.0f - __fdividef(2.0f, 1.0f + __expf(2.0f * v));
}

// Weights -> fragment-linear bf16 for mfma_f32_32x32x16 B-operand.
// Frag F = (g*4 + w)*16 + ks (1 KB each); lane l holds 16 B:
//   W_g[n = w*32 + (l&31)][k = ks*16 + (l>>5)*8 + e], e=0..7
__global__ void wconv_kernel(const float* __restrict__ w1, const float* __restrict__ w2,
                             const float* __restrict__ wf, const float* __restrict__ w3,
                             u32x4* __restrict__ out) {
    int T = blockIdx.x * 256 + threadIdx.x;   // 16384 threads
    int g  = T >> 12;
    int w  = (T >> 10) & 3;
    int ks = (T >> 6) & 15;
    int l  = T & 63;
    const float* W = (g == 0) ? w1 : (g == 1) ? w2 : (g == 2) ? wf : w3;
    const float* s = W + (w * 32 + (l & 31)) * 256 + ks * 16 + (l >> 5) * 8;
    f32x4 lo = *(const f32x4*)s;
    f32x4 hi = *(const f32x4*)(s + 4);
    u32x4 r;
    r[0] = rne1(lo[0]) | (rne1(lo[1]) << 16);
    r[1] = rne1(lo[2]) | (rne1(lo[3]) << 16);
    r[2] = rne1(hi[0]) | (rne1(hi[1]) << 16);
    r[3] = rne1(hi[2]) | (rne1(hi[3]) << 16);
    out[T] = r;
}

// Block = 32 rows, 4 waves. Wave w computes ALL 4 gates for cols [32w,32w+32)
// via mfma_32x32x16; combine fully in-register. A staged fp32 via
// global_load_lds with source-side XOR swizzle (byte ^ ((row&15)<<4)).
__global__ __launch_bounds__(256, 4) void lstm_kernel(
    const float* __restrict__ x, const float* __restrict__ h, const float* __restrict__ c,
    const bf16x8* __restrict__ wfrag,
    const float* __restrict__ b1, const float* __restrict__ b2,
    const float* __restrict__ bfv, const float* __restrict__ b3,
    float* __restrict__ out)
{
    __shared__ __align__(16) char smem[BROWS * 1024];   // 32 rows x 256 fp32, swizzled

    const int tid  = threadIdx.x;
    const int wave = tid >> 6;                // col-slice 0..3
    const int lane = tid & 63;
    const int col  = lane & 31;
    const int hi   = lane >> 5;
    const long b0  = (long)blockIdx.x * BROWS;
    const int  gcol = wave * 32 + col;

    // ---- prefetch c + biases (drain together with the stage at the barrier)
    float cv[16];
#pragma unroll
    for (int r = 0; r < 16; ++r) {
        const int row = (r & 3) + 8 * (r >> 2) + 4 * hi;
        cv[r] = c[(b0 + row) * 128 + gcol];
    }
    const float bias0 = b1[gcol];
    const float bias1 = b2[gcol];
    const float bias2 = bfv[gcol];
    const float bias3 = b3[gcol];

    // ---- async stage: row per (wave,j); lane l copies 16 B.
    // LDS[p] = Atile[p ^ ((row&15)<<4)]  (involution, 16B-chunk granular)
#pragma unroll
    for (int j = 0; j < 8; ++j) {
        const int row = wave * 8 + j;
        const unsigned pl  = (unsigned)lane * 16u;            // byte within row
        const unsigned psw = pl ^ (((unsigned)row & 15u) << 4);
        const int kf = (int)(psw >> 2);                       // float idx 0..255
        const float* src = (kf < 128) ? (x + (b0 + row) * 128 + kf)
                                      : (h + (b0 + row) * 128 + (kf - 128));
        __builtin_amdgcn_global_load_lds(
            (const __attribute__((address_space(1))) unsigned*)src,
            (__attribute__((address_space(3))) unsigned*)(smem + row * 1024),
            16, 0, 0);
    }
    __syncthreads();

    // ---- MFMA: acc[g] = A[32x256] @ Wg[cols 32w..32w+32)^T ----
    f32x16 acc[4];
#pragma unroll
    for (int g = 0; g < 4; ++g) acc[g] = (f32x16)(0.f);

    const bf16x8* wb = wfrag + (size_t)(wave * 16) * 64 + lane;

#pragma unroll
    for (int ks = 0; ks < 16; ++ks) {
        // A-frag: row = col (lane&31), k = ks*16 + hi*8 .. +8 (fp32, swizzled)
        const int k0b = (ks * 16 + hi * 8) * 4;               // byte of k0 in row
        const unsigned sw = ((unsigned)col & 15u) << 4;
        const char* base = smem + col * 1024;
        f32x4 a0 = *(const f32x4*)(base + ((unsigned)k0b ^ sw));
        f32x4 a1 = *(const f32x4*)(base + ((unsigned)(k0b + 16) ^ sw));
        union { unsigned u[4]; bf16x8 v; } pk;
        pk.u[0] = pack2bf(a0[0], a0[1]);
        pk.u[1] = pack2bf(a0[2], a0[3]);
        pk.u[2] = pack2bf(a1[0], a1[1]);
        pk.u[3] = pack2bf(a1[2], a1[3]);
#pragma unroll
        for (int g = 0; g < 4; ++g) {
            bf16x8 bfr = wb[(size_t)(g * 4 * 16 + ks) * 64];
            acc[g] = __builtin_amdgcn_mfma_f32_32x32x16_bf16(pk.v, bfr, acc[g], 0, 0, 0);
        }
    }

    // ---- epilogue: bias+activation+combine in-register, fast math ----
    float* out_h = out;
    float* out_c = out + (size_t)B_TOTAL * HDIM;
#pragma unroll
    for (int r = 0; r < 16; ++r) {
        const int row = (r & 3) + 8 * (r >> 2) + 4 * hi;
        const float g1 = fsig(acc[0][r] + bias0);
        const float g2 = fsig(acc[1][r] + bias1);
        const float gf = ftanh(acc[2][r] + bias2);
        const float g3 = fsig(acc[3][r] + bias3);
        const float nc = cv[r] * g1 + g2 * gf;
        const float nh = ftanh(nc) * g3;
        const long o = (b0 + row) * 128 + gcol;
        out_h[o] = nh;
        out_c[o] = nc;
    }
}

extern "C" void kernel_launch(void* const* d_in, const int* in_sizes, int n_in,
                              void* d_out, int out_size, void* d_ws, size_t ws_size,
                              hipStream_t stream) {
    (void)in_sizes; (void)n_in; (void)out_size; (void)ws_size;
    const float* x  = (const float*)d_in[0];
    const float* h  = (const float*)d_in[1];
    const float* c  = (const float*)d_in[2];
    const float* W1 = (const float*)d_in[3];
    const float* b1 = (const float*)d_in[4];
    const float* W2 = (const float*)d_in[5];
    const float* b2 = (const float*)d_in[6];
    const float* Wf = (const float*)d_in[7];
    const float* bf = (const float*)d_in[8];
    const float* W3 = (const float*)d_in[9];
    const float* b3 = (const float*)d_in[10];

    wconv_kernel<<<64, 256, 0, stream>>>(W1, W2, Wf, W3, (u32x4*)d_ws);
    lstm_kernel<<<B_TOTAL / BROWS, 256, 0, stream>>>(
        x, h, c, (const bf16x8*)d_ws, b1, b2, bf, b3, (float*)d_out);
}

// Round 5
// 36.405 us; speedup vs baseline: 2.0790x; 1.4146x over previous
//
#include <hip/hip_runtime.h>

#define B_TOTAL 32768
#define NROWB   128            // rows per block
#define TILE    32             // rows per tile
#define NT      4              // tiles per block

typedef __attribute__((ext_vector_type(8)))  short    bf16x8;
typedef __attribute__((ext_vector_type(4)))  float    f32x4;
typedef __attribute__((ext_vector_type(4)))  unsigned u32x4;

// round-to-nearest-even fp32 -> bf16 (weights)
__device__ __forceinline__ unsigned rne1(float f) {
    unsigned u = __builtin_bit_cast(unsigned, f);
    return (u + 0x7FFFu + ((u >> 16) & 1u)) >> 16;
}
// fast pack of 2 fp32 -> bf16x2 (A path)
__device__ __forceinline__ unsigned pack2bf(float flo, float fhi) {
    unsigned lo = (__builtin_bit_cast(unsigned, flo) + 0x8000u) >> 16;
    unsigned hi = (__builtin_bit_cast(unsigned, fhi) + 0x8000u) & 0xFFFF0000u;
    return hi | lo;
}
__device__ __forceinline__ float fsig(float v) {
    return __fdividef(1.0f, 1.0f + __expf(-v));
}
__device__ __forceinline__ float ftanh(float v) {
    return 1.0f - __fdividef(2.0f, 1.0f + __expf(2.0f * v));
}

// Weights -> fragment-linear bf16 for mfma_f32_16x16x32 B-operand.
// Frag F = cs*32 + g*8 + ks  (cs=16-col slice 0..7, g=gate, ks=K-step).
// Lane l holds 16 B: W_g[n = cs*16 + (l&15)][k = ks*32 + (l>>4)*8 + e], e=0..7
__global__ void wconv_kernel(const float* __restrict__ w1, const float* __restrict__ w2,
                             const float* __restrict__ wf, const float* __restrict__ w3,
                             u32x4* __restrict__ out) {
    int T = blockIdx.x * 256 + threadIdx.x;   // 16384 threads
    int F = T >> 6, l = T & 63;
    int cs = F >> 5, g = (F >> 3) & 3, ks = F & 7;
    const float* W = (g == 0) ? w1 : (g == 1) ? w2 : (g == 2) ? wf : w3;
    const float* s = W + (cs * 16 + (l & 15)) * 256 + ks * 32 + (l >> 4) * 8;
    f32x4 lo = *(const f32x4*)s;
    f32x4 hi = *(const f32x4*)(s + 4);
    u32x4 r;
    r[0] = rne1(lo[0]) | (rne1(lo[1]) << 16);
    r[1] = rne1(lo[2]) | (rne1(lo[3]) << 16);
    r[2] = rne1(hi[0]) | (rne1(hi[1]) << 16);
    r[3] = rne1(hi[2]) | (rne1(hi[3]) << 16);
    out[T] = r;
}

// Block: 4 waves, 64 output cols (cg*64..), 128 rows as 4 tiles of 32.
// Wave w: col-slice cs = cg*4+w, ALL 4 gates; weights resident in 128 VGPRs.
// A-tile fp32 double-buffered in LDS via global_load_lds (source-XOR swizzle).
__global__ __launch_bounds__(256, 2) void lstm_kernel(
    const float* __restrict__ x, const float* __restrict__ h, const float* __restrict__ c,
    const bf16x8* __restrict__ wfrag,
    const float* __restrict__ b1, const float* __restrict__ b2,
    const float* __restrict__ bfv, const float* __restrict__ b3,
    float* __restrict__ out)
{
    __shared__ __align__(16) char smem[2][TILE * 1024];   // 64 KB

    const int tid  = threadIdx.x;
    const int wave = tid >> 6;
    const int lane = tid & 63;
    const int cg   = blockIdx.x & 1;
    const long row0 = (long)(blockIdx.x >> 1) * NROWB;
    const int cs   = cg * 4 + wave;
    const int gcol = cs * 16 + (lane & 15);

    // ---- stage tile t (32 rows x 256 fp32) into smem[t&1], async ----
    auto STAGE = [&](int t) {
        char* buf = smem[t & 1];
        const long gr0 = row0 + (long)t * TILE;
#pragma unroll
        for (int i = 0; i < 8; ++i) {
            const int r = wave * 8 + i;
            const unsigned kb = ((unsigned)lane * 16u) ^ (((unsigned)r & 7u) << 4);
            const float* src = (kb < 512u)
                ? (x + (gr0 + r) * 128 + (kb >> 2))
                : (h + (gr0 + r) * 128 + ((kb - 512u) >> 2));
            __builtin_amdgcn_global_load_lds(
                (const __attribute__((address_space(1))) unsigned*)src,
                (__attribute__((address_space(3))) unsigned*)(buf + r * 1024),
                16, 0, 0);
        }
    };

    STAGE(0);

    // ---- weights: 4 gates x 8 ks fragments -> 128 VGPRs, loaded once ----
    bf16x8 wfr[4][8];
#pragma unroll
    for (int g = 0; g < 4; ++g)
#pragma unroll
        for (int ks = 0; ks < 8; ++ks)
            wfr[g][ks] = wfrag[(size_t)(cs * 32 + g * 8 + ks) * 64 + lane];

    const float bias0 = b1[gcol];
    const float bias1 = b2[gcol];
    const float bias2 = bfv[gcol];
    const float bias3 = b3[gcol];

    float* out_h = out;
    float* out_c = out + (size_t)B_TOTAL * 128;

#pragma unroll 1
    for (int t = 0; t < NT; ++t) {
        __syncthreads();                  // drains vmcnt -> stage(t) + prev compute done
        if (t + 1 < NT) STAGE(t + 1);     // fills the other buffer under compute(t)

        const char* buf = smem[t & 1];
        const long gr0 = row0 + (long)t * TILE;

        // c prefetch (8 dwords, latency hides under MFMA loop)
        float cv[2][4];
#pragma unroll
        for (int mt = 0; mt < 2; ++mt)
#pragma unroll
            for (int j = 0; j < 4; ++j)
                cv[mt][j] = c[(gr0 + mt * 16 + (lane >> 4) * 4 + j) * 128 + gcol];

        f32x4 acc[2][4];                  // [m-tile][gate]
#pragma unroll
        for (int mt = 0; mt < 2; ++mt)
#pragma unroll
            for (int g = 0; g < 4; ++g)
                acc[mt][g] = (f32x4){0.f, 0.f, 0.f, 0.f};

#pragma unroll
        for (int ks = 0; ks < 8; ++ks) {
            bf16x8 af[2];
#pragma unroll
            for (int mt = 0; mt < 2; ++mt) {
                const int r = mt * 16 + (lane & 15);
                const unsigned swz = ((unsigned)r & 7u) << 4;
                const unsigned kb  = (unsigned)(ks * 128 + (lane >> 4) * 32);
                const char* p = buf + r * 1024;
                f32x4 a0 = *(const f32x4*)(p + (kb ^ swz));
                f32x4 a1 = *(const f32x4*)(p + ((kb + 16u) ^ swz));
                union { unsigned u[4]; bf16x8 v; } pk;
                pk.u[0] = pack2bf(a0[0], a0[1]);
                pk.u[1] = pack2bf(a0[2], a0[3]);
                pk.u[2] = pack2bf(a1[0], a1[1]);
                pk.u[3] = pack2bf(a1[2], a1[3]);
                af[mt] = pk.v;
            }
#pragma unroll
            for (int g = 0; g < 4; ++g) {
                acc[0][g] = __builtin_amdgcn_mfma_f32_16x16x32_bf16(af[0], wfr[g][ks], acc[0][g], 0, 0, 0);
                acc[1][g] = __builtin_amdgcn_mfma_f32_16x16x32_bf16(af[1], wfr[g][ks], acc[1][g], 0, 0, 0);
            }
        }

        // epilogue: fully in-register, fast math
#pragma unroll
        for (int mt = 0; mt < 2; ++mt)
#pragma unroll
            for (int j = 0; j < 4; ++j) {
                const float g1 = fsig(acc[mt][0][j] + bias0);
                const float g2 = fsig(acc[mt][1][j] + bias1);
                const float gf = ftanh(acc[mt][2][j] + bias2);
                const float g3 = fsig(acc[mt][3][j] + bias3);
                const float nc = cv[mt][j] * g1 + g2 * gf;
                const float nh = ftanh(nc) * g3;
                const long o = (gr0 + mt * 16 + (lane >> 4) * 4 + j) * 128 + gcol;
                out_h[o] = nh;
                out_c[o] = nc;
            }
    }
}

extern "C" void kernel_launch(void* const* d_in, const int* in_sizes, int n_in,
                              void* d_out, int out_size, void* d_ws, size_t ws_size,
                              hipStream_t stream) {
    (void)in_sizes; (void)n_in; (void)out_size; (void)ws_size;
    const float* x  = (const float*)d_in[0];
    const float* h  = (const float*)d_in[1];
    const float* c  = (const float*)d_in[2];
    const float* W1 = (const float*)d_in[3];
    const float* b1 = (const float*)d_in[4];
    const float* W2 = (const float*)d_in[5];
    const float* b2 = (const float*)d_in[6];
    const float* Wf = (const float*)d_in[7];
    const float* bf = (const float*)d_in[8];
    const float* W3 = (const float*)d_in[9];
    const float* b3 = (const float*)d_in[10];

    wconv_kernel<<<64, 256, 0, stream>>>(W1, W2, Wf, W3, (u32x4*)d_ws);
    lstm_kernel<<<B_TOTAL / NROWB * 2, 256, 0, stream>>>(
        x, h, c, (const bf16x8*)d_ws, b1, b2, bf, b3, (float*)d_out);
}

// Round 6
// 36.220 us; speedup vs baseline: 2.0897x; 1.0051x over previous
//
#include <hip/hip_runtime.h>

#define B_TOTAL 32768
#define NROWB   128            // rows per block
#define TILE    32             // rows per tile
#define NT      4              // tiles per block

typedef __attribute__((ext_vector_type(8)))  short    bf16x8;
typedef __attribute__((ext_vector_type(4)))  float    f32x4;
typedef __attribute__((ext_vector_type(4)))  unsigned u32x4;

// round-to-nearest-even fp32 -> bf16 (weights, one-time)
__device__ __forceinline__ unsigned rne1(float f) {
    unsigned u = __builtin_bit_cast(unsigned, f);
    return (u + 0x7FFFu + ((u >> 16) & 1u)) >> 16;
}
// HW packed fp32x2 -> bf16x2 (gfx950; no builtin — guide T12 recipe)
__device__ __forceinline__ unsigned cvtpk(float lo, float hi) {
    unsigned r;
    asm("v_cvt_pk_bf16_f32 %0, %1, %2" : "=v"(r) : "v"(lo), "v"(hi));
    return r;
}
__device__ __forceinline__ float fsig(float v) {
    return __fdividef(1.0f, 1.0f + __expf(-v));
}
__device__ __forceinline__ float ftanh(float v) {
    return 1.0f - __fdividef(2.0f, 1.0f + __expf(2.0f * v));
}

// Weights -> fragment-linear bf16 for mfma 16x16x32 (A- or B-operand; same map).
// Frag F = cs*32 + g*8 + ks; lane l: W_g[n = cs*16 + (l&15)][k = ks*32 + (l>>4)*8 + e]
__global__ void wconv_kernel(const float* __restrict__ w1, const float* __restrict__ w2,
                             const float* __restrict__ wf, const float* __restrict__ w3,
                             u32x4* __restrict__ out) {
    int T = blockIdx.x * 256 + threadIdx.x;   // 16384 threads
    int F = T >> 6, l = T & 63;
    int cs = F >> 5, g = (F >> 3) & 3, ks = F & 7;
    const float* W = (g == 0) ? w1 : (g == 1) ? w2 : (g == 2) ? wf : w3;
    const float* s = W + (cs * 16 + (l & 15)) * 256 + ks * 32 + (l >> 4) * 8;
    f32x4 lo = *(const f32x4*)s;
    f32x4 hi = *(const f32x4*)(s + 4);
    u32x4 r;
    r[0] = rne1(lo[0]) | (rne1(lo[1]) << 16);
    r[1] = rne1(lo[2]) | (rne1(lo[3]) << 16);
    r[2] = rne1(hi[0]) | (rne1(hi[1]) << 16);
    r[3] = rne1(hi[2]) | (rne1(hi[3]) << 16);
    out[T] = r;
}

// Block: 4 waves, 64 output cols, 128 rows as 4 tiles of 32.
// Wave w: col-slice cs, ALL 4 gates; weights resident in 128 VGPRs.
// MFMA operands SWAPPED (W as A-operand) so D[gatecol][batchrow]:
// lane holds 4 consecutive gate-cols of one batch row -> float4 epilogue I/O.
__global__ __launch_bounds__(256, 2) void lstm_kernel(
    const float* __restrict__ x, const float* __restrict__ h, const float* __restrict__ c,
    const bf16x8* __restrict__ wfrag,
    const float* __restrict__ b1, const float* __restrict__ b2,
    const float* __restrict__ bfv, const float* __restrict__ b3,
    float* __restrict__ out)
{
    __shared__ __align__(16) char smem[2][TILE * 1024];   // 64 KB

    const int tid  = threadIdx.x;
    const int wave = tid >> 6;
    const int lane = tid & 63;
    const int cg   = blockIdx.x & 1;
    const long row0 = (long)(blockIdx.x >> 1) * NROWB;
    const int cs   = cg * 4 + wave;
    const int rb   = lane & 15;               // batch row within 16
    const int gcol4 = cs * 16 + (lane >> 4) * 4;  // 4 consecutive gate cols

    // ---- stage tile t (32 rows x 256 fp32) into smem[t&1], async ----
    auto STAGE = [&](int t) {
        char* buf = smem[t & 1];
        const long gr0 = row0 + (long)t * TILE;
#pragma unroll
        for (int i = 0; i < 8; ++i) {
            const int r = wave * 8 + i;
            const unsigned kb = ((unsigned)lane * 16u) ^ (((unsigned)r & 7u) << 4);
            const float* src = (kb < 512u)
                ? (x + (gr0 + r) * 128 + (kb >> 2))
                : (h + (gr0 + r) * 128 + ((kb - 512u) >> 2));
            __builtin_amdgcn_global_load_lds(
                (const __attribute__((address_space(1))) unsigned*)src,
                (__attribute__((address_space(3))) unsigned*)(buf + r * 1024),
                16, 0, 0);
        }
    };

    STAGE(0);

    // ---- weights: 4 gates x 8 ks fragments -> 128 VGPRs, loaded once ----
    bf16x8 wfr[4][8];
#pragma unroll
    for (int g = 0; g < 4; ++g)
#pragma unroll
        for (int ks = 0; ks < 8; ++ks)
            wfr[g][ks] = wfrag[(size_t)(cs * 32 + g * 8 + ks) * 64 + lane];

    // biases: 4 consecutive cols per gate
    f32x4 bias[4];
    bias[0] = *(const f32x4*)(b1 + gcol4);
    bias[1] = *(const f32x4*)(b2 + gcol4);
    bias[2] = *(const f32x4*)(bfv + gcol4);
    bias[3] = *(const f32x4*)(b3 + gcol4);

    float* out_h = out;
    float* out_c = out + (size_t)B_TOTAL * 128;

#pragma unroll 1
    for (int t = 0; t < NT; ++t) {
        __syncthreads();                  // drains vmcnt: stage(t) done, buf(t+1) free
        if (t + 1 < NT) STAGE(t + 1);

        const char* buf = smem[t & 1];
        const long gr0 = row0 + (long)t * TILE;

        // c prefetch: float4, latency hides under MFMA loop
        f32x4 cv[2];
#pragma unroll
        for (int mt = 0; mt < 2; ++mt)
            cv[mt] = *(const f32x4*)(c + (gr0 + mt * 16 + rb) * 128 + gcol4);

        f32x4 acc[2][4];                  // [m-tile][gate]
#pragma unroll
        for (int mt = 0; mt < 2; ++mt)
#pragma unroll
            for (int g = 0; g < 4; ++g)
                acc[mt][g] = (f32x4){0.f, 0.f, 0.f, 0.f};

#pragma unroll
        for (int ks = 0; ks < 8; ++ks) {
            bf16x8 af[2];
#pragma unroll
            for (int mt = 0; mt < 2; ++mt) {
                const int r = mt * 16 + rb;
                const unsigned swz = ((unsigned)r & 7u) << 4;
                const unsigned kb  = (unsigned)(ks * 128 + (lane >> 4) * 32);
                const char* p = buf + r * 1024;
                f32x4 a0 = *(const f32x4*)(p + (kb ^ swz));
                f32x4 a1 = *(const f32x4*)(p + ((kb + 16u) ^ swz));
                union { unsigned u[4]; bf16x8 v; } pk;
                pk.u[0] = cvtpk(a0[0], a0[1]);
                pk.u[1] = cvtpk(a0[2], a0[3]);
                pk.u[2] = cvtpk(a1[0], a1[1]);
                pk.u[3] = cvtpk(a1[2], a1[3]);
                af[mt] = pk.v;
            }
#pragma unroll
            for (int g = 0; g < 4; ++g) {
                // swapped operands: D[gatecol][batchrow]
                acc[0][g] = __builtin_amdgcn_mfma_f32_16x16x32_bf16(wfr[g][ks], af[0], acc[0][g], 0, 0, 0);
                acc[1][g] = __builtin_amdgcn_mfma_f32_16x16x32_bf16(wfr[g][ks], af[1], acc[1][g], 0, 0, 0);
            }
        }

        // epilogue: in-register combine, float4 stores
#pragma unroll
        for (int mt = 0; mt < 2; ++mt) {
            f32x4 nh, nc;
#pragma unroll
            for (int j = 0; j < 4; ++j) {
                const float g1 = fsig(acc[mt][0][j] + bias[0][j]);
                const float g2 = fsig(acc[mt][1][j] + bias[1][j]);
                const float gf = ftanh(acc[mt][2][j] + bias[2][j]);
                const float g3 = fsig(acc[mt][3][j] + bias[3][j]);
                nc[j] = cv[mt][j] * g1 + g2 * gf;
                nh[j] = ftanh(nc[j]) * g3;
            }
            const long o = (gr0 + mt * 16 + rb) * 128 + gcol4;
            *(f32x4*)(out_h + o) = nh;
            *(f32x4*)(out_c + o) = nc;
        }
    }
}

extern "C" void kernel_launch(void* const* d_in, const int* in_sizes, int n_in,
                              void* d_out, int out_size, void* d_ws, size_t ws_size,
                              hipStream_t stream) {
    (void)in_sizes; (void)n_in; (void)out_size; (void)ws_size;
    const float* x  = (const float*)d_in[0];
    const float* h  = (const float*)d_in[1];
    const float* c  = (const float*)d_in[2];
    const float* W1 = (const float*)d_in[3];
    const float* b1 = (const float*)d_in[4];
    const float* W2 = (const float*)d_in[5];
    const float* b2 = (const float*)d_in[6];
    const float* Wf = (const float*)d_in[7];
    const float* bf = (const float*)d_in[8];
    const float* W3 = (const float*)d_in[9];
    const float* b3 = (const float*)d_in[10];

    wconv_kernel<<<64, 256, 0, stream>>>(W1, W2, Wf, W3, (u32x4*)d_ws);
    lstm_kernel<<<B_TOTAL / NROWB * 2, 256, 0, stream>>>(
        x, h, c, (const bf16x8*)d_ws, b1, b2, bf, b3, (float*)d_out);
}